// Round 14
// baseline (73.007 us; speedup 1.0000x reference)
//
#include <hip/hip_runtime.h>
#include <hip/hip_bf16.h>

#define NN 50000
#define CH 64
#define NB 1563          // ceil(NN/32) coarse buckets of 32 nodes
#define NBLK 256         // sort-role blocks (1 edge-chunk each)
#define MAXPT 13         // ceil(chunk/256) edges per thread in sort role

typedef __attribute__((ext_vector_type(8))) short short8;  // 8 bf16 (4 VGPRs)
typedef __attribute__((ext_vector_type(4))) float f32x4;   // MFMA 16x16 acc

__device__ __forceinline__ unsigned short f2bf(float f) {
    __hip_bfloat16 h = __float2bfloat16(f);
    return *reinterpret_cast<unsigned short*>(&h);
}

// ---------- ws layout (bytes; ws is 256 MiB) ----------
// msgb   : [0, 6.4MB)        uint[NN*32] — bf16x2-packed x@Wn + bn
// sorted : [12.8M, +3.2MB)   int[E] packed (dst&31)<<16|src, BLOCK-MAJOR
// off    : [16.0M, +1.6MB)   int[NBLK][NB+1] per-block bucket offsets
// wfrag  : [17.7M, +16KB)    bf16 fragment-major [ni(8)][kstep(2)][lane(64)][8]

// ---------------- k_prep: W -> fragment-major bf16 (B-operand of MFMA)
__global__ __launch_bounds__(128) void k_prep(
    const float* __restrict__ Ws, const float* __restrict__ Wn,
    uint4* __restrict__ wfrag)
{
    const int ni = blockIdx.x;        // 0..7 (output 16-col tile)
    const int t  = threadIdx.x;       // 0..127
    const int ks = t >> 6, l = t & 63;
    const int c16 = l & 15, kg = l >> 4;
    const int k0 = ks * 32 + kg * 8;
    const float* B = (ni < 4) ? Ws : Wn;
    const int c = ((ni < 4) ? ni : ni - 4) * 16 + c16;
    unsigned int w4[4];
#pragma unroll
    for (int jj = 0; jj < 4; jj++) {
        const unsigned short lo = f2bf(B[(k0 + 2 * jj)     * CH + c]);
        const unsigned short hi = f2bf(B[(k0 + 2 * jj + 1) * CH + c]);
        w4[jj] = (unsigned int)lo | ((unsigned int)hi << 16);
    }
    wfrag[(ni * 2 + ks) * 64 + l] = make_uint4(w4[0], w4[1], w4[2], w4[3]);
}

// ---------------- k_main: blocks [0,NBLK) = local counting sort (single read);
//                  blocks [NBLK, NBLK+1563) = MFMA dual projection (no LDS)
__global__ __launch_bounds__(256) void k_main(
    const int* __restrict__ rows, const int* __restrict__ cols,
    int* __restrict__ sorted, int* __restrict__ off, int E,
    const float* __restrict__ x,
    const float* __restrict__ bself, const float* __restrict__ bneigh,
    const short8* __restrict__ wfrag,
    float* __restrict__ hout, unsigned int* __restrict__ mout)
{
    __shared__ int smem[2 * NB + 1 + 3200];   // sort role only (~25.3 KB)
    __shared__ int wsum[8];
    const int tid = threadIdx.x;
    const int lane = tid & 63, wid = tid >> 6;

    if (blockIdx.x < NBLK) {
        // ---- sort role: one global pass; edges live in registers
        int* lh     = smem;                   // [NB] hist, later cursors
        int* loff   = smem + NB;              // [NB+1] exclusive offsets
        int* staged = smem + 2 * NB + 1;      // [chunk<=3200]
        const int b = blockIdx.x;
        const int chunk = (E + NBLK - 1) / NBLK;
        const int beg = b * chunk;
        const int fin = min(beg + chunk, E);

        int ec[MAXPT], er[MAXPT];             // compile-time indexed -> VGPRs
#pragma unroll
        for (int u = 0; u < MAXPT; u++) {
            const int i = beg + tid + u * 256;
            if (i < fin) { ec[u] = cols[i]; er[u] = rows[i]; }
            else         { ec[u] = -1;      er[u] = 0; }
        }

        for (int k = tid; k < NB; k += 256) lh[k] = 0;
        __syncthreads();
#pragma unroll
        for (int u = 0; u < MAXPT; u++)
            if (ec[u] >= 0) atomicAdd(&lh[ec[u] >> 5], 1);
        __syncthreads();

        int carry = 0;
        for (int base = 0; base < NB; base += 256) {
            const int i = base + tid;
            const int v = (i < NB) ? lh[i] : 0;
            int s = v;
#pragma unroll
            for (int d = 1; d < 64; d <<= 1) {
                int t = __shfl_up(s, d);
                if (lane >= d) s += t;
            }
            if (lane == 63) wsum[wid] = s;
            __syncthreads();
            if (tid == 0) {
                int a = 0;
#pragma unroll
                for (int w = 0; w < 4; w++) { int t = wsum[w]; wsum[w] = a; a += t; }
                wsum[4] = a;
            }
            __syncthreads();
            if (i < NB) loff[i] = carry + wsum[wid] + (s - v);
            carry += wsum[4];
            __syncthreads();
        }
        if (tid == 0) loff[NB] = carry;
        __syncthreads();

        for (int k = tid; k < NB; k += 256) lh[k] = loff[k];
        __syncthreads();
#pragma unroll
        for (int u = 0; u < MAXPT; u++) {
            if (ec[u] >= 0) {
                const int pos = atomicAdd(&lh[ec[u] >> 5], 1);
                staged[pos] = ((ec[u] & 31) << 16) | er[u];   // src < 2^16
            }
        }
        __syncthreads();
        const int cnt = fin - beg;
        for (int i = tid; i < cnt; i += 256) sorted[beg + i] = staged[i];
        for (int k = tid; k < NB + 1; k += 256) off[b * (NB + 1) + k] = loff[k];
        return;
    }

    // ---- projection role: C[32x128] = xtile @ [Ws|Wn] via 16x16x32 bf16 MFMA
    const int node0 = (blockIdx.x - NBLK) * 32;
    const int mi = wid & 1;               // output row 16-tile
    const int niBase = (wid >> 1) * 4;    // 4 col-tiles per wave
    const int c16 = lane & 15, kg = lane >> 4;

    int arow = node0 + mi * 16 + c16;
    if (arow > NN - 1) arow = NN - 1;
    const size_t abase = (size_t)arow * CH;
    short8 af[2];
#pragma unroll
    for (int ks = 0; ks < 2; ks++) {
        const float4 p = *(const float4*)&x[abase + ks * 32 + kg * 8];
        const float4 q = *(const float4*)&x[abase + ks * 32 + kg * 8 + 4];
        short8 a;
        a[0] = (short)f2bf(p.x); a[1] = (short)f2bf(p.y);
        a[2] = (short)f2bf(p.z); a[3] = (short)f2bf(p.w);
        a[4] = (short)f2bf(q.x); a[5] = (short)f2bf(q.y);
        a[6] = (short)f2bf(q.z); a[7] = (short)f2bf(q.w);
        af[ks] = a;
    }

    f32x4 acc[4];
#pragma unroll
    for (int t2 = 0; t2 < 4; t2++) {
        const int ni = niBase + t2;
        const float bias = (ni < 4) ? bself[ni * 16 + c16]
                                    : bneigh[(ni - 4) * 16 + c16];
        acc[t2] = (f32x4){bias, bias, bias, bias};
#pragma unroll
        for (int ks = 0; ks < 2; ks++) {
            const short8 bf = wfrag[(ni * 2 + ks) * 64 + lane];
            acc[t2] = __builtin_amdgcn_mfma_f32_16x16x32_bf16(af[ks], bf,
                                                              acc[t2], 0, 0, 0);
        }
    }

#pragma unroll
    for (int t2 = 0; t2 < 4; t2++) {
        const int ni = niBase + t2;
#pragma unroll
        for (int r = 0; r < 4; r++) {
            const int node = node0 + mi * 16 + kg * 4 + r;
            const float v = acc[t2][r];
            if (ni < 4) {
                if (node < NN)
                    hout[(size_t)node * CH + ni * 16 + c16] = v;
            } else {
                const float partner = __shfl_xor(v, 1);
                if (node < NN && (lane & 1) == 0) {
                    const unsigned int pk = (unsigned int)f2bf(v)
                                          | ((unsigned int)f2bf(partner) << 16);
                    mout[(size_t)node * 32 + (ni - 4) * 8 + (c16 >> 1)] = pk;
                }
            }
        }
    }
}

// ---------------- k_gfin3: one block per bucket (32 nodes), 512 threads.
// Wave-parallel segment staging, fine counting-sort, bf16x2 gather, relu.
__global__ __launch_bounds__(512) void k_gfin3(
    const unsigned int* __restrict__ mb, const int* __restrict__ off,
    const int* __restrict__ sorted, float* __restrict__ out, int E)
{
    __shared__ int pairs[4096];
    __shared__ unsigned short srcs[4096];
    __shared__ int segdst[257];
    __shared__ int segsrc[256];
    __shared__ int fh[32], foff[33], fcur[32];
    __shared__ int wsum[8];

    const int g = blockIdx.x;
    const int tid = threadIdx.x;
    const int lane = tid & 63, wave = tid >> 6;
    const int chunk = (E + NBLK - 1) / NBLK;

    // ---- segment-count scan (threads 0..255 own segment = source block)
    int mycnt = 0;
    if (tid < 256) {
        const int s0 = off[tid * (NB + 1) + g];
        mycnt = off[tid * (NB + 1) + g + 1] - s0;
        segsrc[tid] = tid * chunk + s0;
    }
    {
        int s = mycnt;
#pragma unroll
        for (int d = 1; d < 64; d <<= 1) {
            int t = __shfl_up(s, d);
            if (lane >= d) s += t;
        }
        if (tid < 256 && lane == 63) wsum[wave] = s;
        __syncthreads();
        if (tid == 0) {
            int a = 0;
#pragma unroll
            for (int w = 0; w < 4; w++) { int t = wsum[w]; wsum[w] = a; a += t; }
            wsum[4] = a;
        }
        __syncthreads();
        if (tid < 256) segdst[tid] = wsum[wave] + (s - mycnt);
        if (tid == 0) segdst[256] = wsum[4];
    }
    __syncthreads();
    const int cn = min(segdst[256], 4096);

    // ---- wave-parallel staging: wave w copies segments w, w+8, ... lane-parallel
    for (int sg = wave; sg < 256; sg += 8) {
        const int d0 = segdst[sg];
        const int sc = segdst[sg + 1] - d0;
        const int sp = segsrc[sg];
        for (int j = lane; j < sc; j += 64) {
            const int dst = d0 + j;
            if (dst < 4096) pairs[dst] = sorted[sp + j];
        }
    }
    __syncthreads();

    // ---- fine counting-sort by local dest (LDS)
    if (tid < 32) fh[tid] = 0;
    __syncthreads();
    for (int i = tid; i < cn; i += 512)
        atomicAdd(&fh[pairs[i] >> 16], 1);
    __syncthreads();
    if (tid < 64) {
        const int v = (lane < 32) ? fh[lane] : 0;
        int s = v;
#pragma unroll
        for (int d = 1; d < 32; d <<= 1) {
            int t = __shfl_up(s, d);
            if (lane >= d) s += t;
        }
        if (lane < 32) { foff[lane] = s - v; fcur[lane] = s - v; }
        if (lane == 0) foff[32] = cn;
    }
    __syncthreads();
    for (int i = tid; i < cn; i += 512) {
        const int p = pairs[i];
        const int pos = atomicAdd(&fcur[p >> 16], 1);
        srcs[pos] = (unsigned short)(p & 0xFFFF);
    }
    __syncthreads();

    // ---- gather: wave = 4 local nodes; 2 edges at once via 32-lane halves
    const int c2 = lane & 31;
    const int half = lane >> 5;
    float accL[4], accH[4];
#pragma unroll
    for (int r = 0; r < 4; r++) { accL[r] = 0.f; accH[r] = 0.f; }

#pragma unroll
    for (int r = 0; r < 4; r++) {
        const int nl = wave * 4 + r;
        const int j0 = foff[nl], j1 = foff[nl + 1];
        float l0 = 0.f, l1 = 0.f, l2 = 0.f, l3 = 0.f;
        float h0 = 0.f, h1 = 0.f, h2 = 0.f, h3 = 0.f;
        int j = j0 + half;
        for (; j + 6 < j1; j += 8) {
            const unsigned int v0 = mb[(int)srcs[j]     * 32 + c2];
            const unsigned int v1 = mb[(int)srcs[j + 2] * 32 + c2];
            const unsigned int v2 = mb[(int)srcs[j + 4] * 32 + c2];
            const unsigned int v3 = mb[(int)srcs[j + 6] * 32 + c2];
            l0 += __uint_as_float(v0 << 16); h0 += __uint_as_float(v0 & 0xFFFF0000u);
            l1 += __uint_as_float(v1 << 16); h1 += __uint_as_float(v1 & 0xFFFF0000u);
            l2 += __uint_as_float(v2 << 16); h2 += __uint_as_float(v2 & 0xFFFF0000u);
            l3 += __uint_as_float(v3 << 16); h3 += __uint_as_float(v3 & 0xFFFF0000u);
        }
        for (; j < j1; j += 2) {
            const unsigned int v = mb[(int)srcs[j] * 32 + c2];
            l0 += __uint_as_float(v << 16); h0 += __uint_as_float(v & 0xFFFF0000u);
        }
        accL[r] += (l0 + l1) + (l2 + l3);
        accH[r] += (h0 + h1) + (h2 + h3);
    }

#pragma unroll
    for (int r = 0; r < 4; r++) {
        accL[r] += __shfl_xor(accL[r], 32);
        accH[r] += __shfl_xor(accH[r], 32);
        const int nd = g * 32 + wave * 4 + r;
        if (nd < NN) {
            const int o = nd * CH + 2 * c2 + half;
            const float myv = half ? accH[r] : accL[r];
            out[o] = fmaxf(out[o] + myv, 0.f);
        }
    }
}

extern "C" void kernel_launch(void* const* d_in, const int* in_sizes, int n_in,
                              void* d_out, int out_size, void* d_ws, size_t ws_size,
                              hipStream_t stream)
{
    const float* x      = (const float*)d_in[0];
    const int*   edges  = (const int*)d_in[1];
    const float* Wself  = (const float*)d_in[2];
    const float* bself  = (const float*)d_in[3];
    const float* Wneigh = (const float*)d_in[4];
    const float* bneigh = (const float*)d_in[5];
    float* out = (float*)d_out;

    const int E = in_sizes[1] / 2;
    const int* rows = edges;        // edge_index[0] (sources)
    const int* cols = edges + E;    // edge_index[1] (destinations)

    char* ws_base = (char*)d_ws;
    unsigned int* msgb = (unsigned int*)(ws_base);         // 6.4 MB (bf16x2)
    int*   sorted = (int*)(ws_base + 12800000);            // 3.2 MB block-major
    int*   off    = (int*)(ws_base + 16000000);            // 1.6 MB
    uint4* wfrag  = (uint4*)(ws_base + 17700000);          // 16 KB frag-major W

    k_prep<<<8, 128, 0, stream>>>(Wself, Wneigh, wfrag);

    const int bP = (NN + 31) / 32;   // 1563 proj blocks
    k_main<<<NBLK + bP, 256, 0, stream>>>(rows, cols, sorted, off, E,
                                          x, bself, bneigh,
                                          (const short8*)wfrag, out, msgb);
    k_gfin3<<<NB, 512, 0, stream>>>(msgb, off, sorted, out, E);
}

// Round 15
// 52.376 us; speedup vs baseline: 1.3939x; 1.3939x over previous
//
#include <hip/hip_runtime.h>
#include <hip/hip_bf16.h>

#define NN 50000
#define CH 64
#define NB 1563          // ceil(NN/32) coarse buckets of 32 nodes
#define NBLK 256         // sort-role blocks (1 edge-chunk each)
#define MAXPT 13         // ceil(chunk/256) edges per thread in sort role

typedef __attribute__((ext_vector_type(8))) short short8;  // 8 bf16 (4 VGPRs)
typedef __attribute__((ext_vector_type(4))) float f32x4;   // MFMA 16x16 acc

__device__ __forceinline__ unsigned short f2bf(float f) {
    __hip_bfloat16 h = __float2bfloat16(f);
    return *reinterpret_cast<unsigned short*>(&h);
}

// ---------- ws layout (bytes; ws is 256 MiB) ----------
// msgb   : [0, 6.4MB)        uint[NN*32] — bf16x2-packed x@Wn + bn
// sorted : [12.8M, +3.2MB)   int[E] packed (dst&31)<<16|src, BLOCK-MAJOR
// off    : [16.0M, +1.6MB)   int[NBLK][NB+1] per-block bucket offsets
// wfrag  : [17.7M, +16KB)    bf16 fragment-major [ni(8)][kstep(2)][lane(64)][8]

// ---------------- k_prep: W -> fragment-major bf16 (B-operand of MFMA)
__global__ __launch_bounds__(128) void k_prep(
    const float* __restrict__ Ws, const float* __restrict__ Wn,
    uint4* __restrict__ wfrag)
{
    const int ni = blockIdx.x;        // 0..7 (output 16-col tile)
    const int t  = threadIdx.x;       // 0..127
    const int ks = t >> 6, l = t & 63;
    const int c16 = l & 15, kg = l >> 4;
    const int k0 = ks * 32 + kg * 8;
    const float* B = (ni < 4) ? Ws : Wn;
    const int c = ((ni < 4) ? ni : ni - 4) * 16 + c16;
    unsigned int w4[4];
#pragma unroll
    for (int jj = 0; jj < 4; jj++) {
        const unsigned short lo = f2bf(B[(k0 + 2 * jj)     * CH + c]);
        const unsigned short hi = f2bf(B[(k0 + 2 * jj + 1) * CH + c]);
        w4[jj] = (unsigned int)lo | ((unsigned int)hi << 16);
    }
    wfrag[(ni * 2 + ks) * 64 + l] = make_uint4(w4[0], w4[1], w4[2], w4[3]);
}

// ---------------- k_main: blocks [0,NBLK) = local counting sort (single read);
//                  blocks [NBLK, NBLK+1563) = MFMA dual projection (no LDS)
__global__ __launch_bounds__(256) void k_main(
    const int* __restrict__ rows, const int* __restrict__ cols,
    int* __restrict__ sorted, int* __restrict__ off, int E,
    const float* __restrict__ x,
    const float* __restrict__ bself, const float* __restrict__ bneigh,
    const short8* __restrict__ wfrag,
    float* __restrict__ hout, unsigned int* __restrict__ mout)
{
    __shared__ int smem[2 * NB + 1 + 3200];   // sort role only (~25.3 KB)
    __shared__ int wsum[8];
    const int tid = threadIdx.x;
    const int lane = tid & 63, wid = tid >> 6;

    if (blockIdx.x < NBLK) {
        // ---- sort role: one global pass; edges live in registers
        int* lh     = smem;                   // [NB] hist, later cursors
        int* loff   = smem + NB;              // [NB+1] exclusive offsets
        int* staged = smem + 2 * NB + 1;      // [chunk<=3200]
        const int b = blockIdx.x;
        const int chunk = (E + NBLK - 1) / NBLK;
        const int beg = b * chunk;
        const int fin = min(beg + chunk, E);

        int ec[MAXPT], er[MAXPT];             // compile-time indexed -> VGPRs
#pragma unroll
        for (int u = 0; u < MAXPT; u++) {
            const int i = beg + tid + u * 256;
            if (i < fin) { ec[u] = cols[i]; er[u] = rows[i]; }
            else         { ec[u] = -1;      er[u] = 0; }
        }

        for (int k = tid; k < NB; k += 256) lh[k] = 0;
        __syncthreads();
#pragma unroll
        for (int u = 0; u < MAXPT; u++)
            if (ec[u] >= 0) atomicAdd(&lh[ec[u] >> 5], 1);
        __syncthreads();

        int carry = 0;
        for (int base = 0; base < NB; base += 256) {
            const int i = base + tid;
            const int v = (i < NB) ? lh[i] : 0;
            int s = v;
#pragma unroll
            for (int d = 1; d < 64; d <<= 1) {
                int t = __shfl_up(s, d);
                if (lane >= d) s += t;
            }
            if (lane == 63) wsum[wid] = s;
            __syncthreads();
            if (tid == 0) {
                int a = 0;
#pragma unroll
                for (int w = 0; w < 4; w++) { int t = wsum[w]; wsum[w] = a; a += t; }
                wsum[4] = a;
            }
            __syncthreads();
            if (i < NB) loff[i] = carry + wsum[wid] + (s - v);
            carry += wsum[4];
            __syncthreads();
        }
        if (tid == 0) loff[NB] = carry;
        __syncthreads();

        for (int k = tid; k < NB; k += 256) lh[k] = loff[k];
        __syncthreads();
#pragma unroll
        for (int u = 0; u < MAXPT; u++) {
            if (ec[u] >= 0) {
                const int pos = atomicAdd(&lh[ec[u] >> 5], 1);
                staged[pos] = ((ec[u] & 31) << 16) | er[u];   // src < 2^16
            }
        }
        __syncthreads();
        const int cnt = fin - beg;
        for (int i = tid; i < cnt; i += 256) sorted[beg + i] = staged[i];
        for (int k = tid; k < NB + 1; k += 256) off[b * (NB + 1) + k] = loff[k];
        return;
    }

    // ---- projection role: C[32x128] = xtile @ [Ws|Wn] via 16x16x32 bf16 MFMA
    const int node0 = (blockIdx.x - NBLK) * 32;
    const int mi = wid & 1;               // output row 16-tile
    const int niBase = (wid >> 1) * 4;    // 4 col-tiles per wave
    const int c16 = lane & 15, kg = lane >> 4;

    int arow = node0 + mi * 16 + c16;
    if (arow > NN - 1) arow = NN - 1;
    const size_t abase = (size_t)arow * CH;
    short8 af[2];
#pragma unroll
    for (int ks = 0; ks < 2; ks++) {
        const float4 p = *(const float4*)&x[abase + ks * 32 + kg * 8];
        const float4 q = *(const float4*)&x[abase + ks * 32 + kg * 8 + 4];
        short8 a;
        a[0] = (short)f2bf(p.x); a[1] = (short)f2bf(p.y);
        a[2] = (short)f2bf(p.z); a[3] = (short)f2bf(p.w);
        a[4] = (short)f2bf(q.x); a[5] = (short)f2bf(q.y);
        a[6] = (short)f2bf(q.z); a[7] = (short)f2bf(q.w);
        af[ks] = a;
    }

    f32x4 acc[4];
#pragma unroll
    for (int t2 = 0; t2 < 4; t2++) {
        const int ni = niBase + t2;
        const float bias = (ni < 4) ? bself[ni * 16 + c16]
                                    : bneigh[(ni - 4) * 16 + c16];
        acc[t2] = (f32x4){bias, bias, bias, bias};
#pragma unroll
        for (int ks = 0; ks < 2; ks++) {
            const short8 bf = wfrag[(ni * 2 + ks) * 64 + lane];
            acc[t2] = __builtin_amdgcn_mfma_f32_16x16x32_bf16(af[ks], bf,
                                                              acc[t2], 0, 0, 0);
        }
    }

#pragma unroll
    for (int t2 = 0; t2 < 4; t2++) {
        const int ni = niBase + t2;
#pragma unroll
        for (int r = 0; r < 4; r++) {
            const int node = node0 + mi * 16 + kg * 4 + r;
            const float v = acc[t2][r];
            if (ni < 4) {
                if (node < NN)
                    hout[(size_t)node * CH + ni * 16 + c16] = v;
            } else {
                const float partner = __shfl_xor(v, 1);
                if (node < NN && (lane & 1) == 0) {
                    const unsigned int pk = (unsigned int)f2bf(v)
                                          | ((unsigned int)f2bf(partner) << 16);
                    mout[(size_t)node * 32 + (ni - 4) * 8 + (c16 >> 1)] = pk;
                }
            }
        }
    }
}

// ---------------- k_gfin3: one block per bucket (32 nodes), 512 threads.
// Per-thread segment staging (proven), fine counting-sort, then uint2 gather:
// quarter-wave per edge (qw = edge parity 0..3, c4 = 4-channel group), 2-deep
// unroll -> 8 edges in flight per wave; float4 coalesced RMW epilogue.
__global__ __launch_bounds__(512) void k_gfin3(
    const unsigned int* __restrict__ mb, const int* __restrict__ off,
    const int* __restrict__ sorted, float* __restrict__ out, int E)
{
    __shared__ int pairs[4096];
    __shared__ unsigned short srcs[4096];
    __shared__ int segend[257];
    __shared__ int fh[32], foff[33], fcur[32];
    __shared__ int wsum[8];

    const int g = blockIdx.x;
    const int tid = threadIdx.x;
    const int lane = tid & 63, wave = tid >> 6;
    const int chunk = (E + NBLK - 1) / NBLK;

    // ---- segment-count scan + per-thread staging (threads 0..255)
    int s0 = 0, mycnt = 0;
    if (tid < 256) {
        s0    = off[tid * (NB + 1) + g];
        mycnt = off[tid * (NB + 1) + g + 1] - s0;
    }
    {
        int s = mycnt;
#pragma unroll
        for (int d = 1; d < 64; d <<= 1) {
            int t = __shfl_up(s, d);
            if (lane >= d) s += t;
        }
        if (tid < 256 && lane == 63) wsum[wave] = s;
        __syncthreads();
        if (tid == 0) {
            int a = 0;
#pragma unroll
            for (int w = 0; w < 4; w++) { int t = wsum[w]; wsum[w] = a; a += t; }
            wsum[4] = a;
        }
        __syncthreads();
        if (tid < 256) {
            const int myoff = wsum[wave] + (s - mycnt);
            const int src = tid * chunk + s0;
            for (int j = 0; j < mycnt; j++) {
                const int dst = myoff + j;
                if (dst < 4096) pairs[dst] = sorted[src + j];
            }
        }
        if (tid == 0) segend[256] = wsum[4];
    }
    __syncthreads();
    const int cn = min(segend[256], 4096);

    // ---- fine counting-sort by local dest (LDS)
    if (tid < 32) fh[tid] = 0;
    __syncthreads();
    for (int i = tid; i < cn; i += 512)
        atomicAdd(&fh[pairs[i] >> 16], 1);
    __syncthreads();
    if (tid < 64) {
        const int v = (lane < 32) ? fh[lane] : 0;
        int s = v;
#pragma unroll
        for (int d = 1; d < 32; d <<= 1) {
            int t = __shfl_up(s, d);
            if (lane >= d) s += t;
        }
        if (lane < 32) { foff[lane] = s - v; fcur[lane] = s - v; }
        if (lane == 0) foff[32] = cn;
    }
    __syncthreads();
    for (int i = tid; i < cn; i += 512) {
        const int p = pairs[i];
        const int pos = atomicAdd(&fcur[p >> 16], 1);
        srcs[pos] = (unsigned short)(p & 0xFFFF);
    }
    __syncthreads();

    // ---- gather: wave = 4 local nodes; quarter-wave per edge, uint2 loads
    const unsigned long long* mb2 = (const unsigned long long*)mb;  // 8B rows/16
    const int qw = lane >> 4;        // edge parity 0..3
    const int c4 = lane & 15;        // 4-channel group
    float a0[4], a1[4], a2[4], a3[4];
#pragma unroll
    for (int r = 0; r < 4; r++) { a0[r]=0.f; a1[r]=0.f; a2[r]=0.f; a3[r]=0.f; }

#pragma unroll
    for (int r = 0; r < 4; r++) {
        const int nl = wave * 4 + r;
        const int j0 = foff[nl], j1 = foff[nl + 1];
        float s0_=0.f, s1_=0.f, s2_=0.f, s3_=0.f;
        float t0_=0.f, t1_=0.f, t2_=0.f, t3_=0.f;
        int j = j0 + qw;
        for (; j + 4 < j1; j += 8) {
            const unsigned long long v0 = mb2[(int)srcs[j]     * 16 + c4];
            const unsigned long long v1 = mb2[(int)srcs[j + 4] * 16 + c4];
            const unsigned int x0 = (unsigned int)v0, y0 = (unsigned int)(v0 >> 32);
            const unsigned int x1 = (unsigned int)v1, y1 = (unsigned int)(v1 >> 32);
            s0_ += __uint_as_float(x0 << 16); s1_ += __uint_as_float(x0 & 0xFFFF0000u);
            s2_ += __uint_as_float(y0 << 16); s3_ += __uint_as_float(y0 & 0xFFFF0000u);
            t0_ += __uint_as_float(x1 << 16); t1_ += __uint_as_float(x1 & 0xFFFF0000u);
            t2_ += __uint_as_float(y1 << 16); t3_ += __uint_as_float(y1 & 0xFFFF0000u);
        }
        if (j < j1) {
            const unsigned long long v0 = mb2[(int)srcs[j] * 16 + c4];
            const unsigned int x0 = (unsigned int)v0, y0 = (unsigned int)(v0 >> 32);
            s0_ += __uint_as_float(x0 << 16); s1_ += __uint_as_float(x0 & 0xFFFF0000u);
            s2_ += __uint_as_float(y0 << 16); s3_ += __uint_as_float(y0 & 0xFFFF0000u);
        }
        a0[r] = s0_ + t0_; a1[r] = s1_ + t1_;
        a2[r] = s2_ + t2_; a3[r] = s3_ + t3_;
    }

    // ---- cross-quarter reduce + coalesced float4 RMW by quarter 0
#pragma unroll
    for (int r = 0; r < 4; r++) {
        a0[r] += __shfl_xor(a0[r], 16); a0[r] += __shfl_xor(a0[r], 32);
        a1[r] += __shfl_xor(a1[r], 16); a1[r] += __shfl_xor(a1[r], 32);
        a2[r] += __shfl_xor(a2[r], 16); a2[r] += __shfl_xor(a2[r], 32);
        a3[r] += __shfl_xor(a3[r], 16); a3[r] += __shfl_xor(a3[r], 32);
        const int nd = g * 32 + wave * 4 + r;
        if (qw == 0 && nd < NN) {
            float4* po = (float4*)&out[(size_t)nd * CH + c4 * 4];
            float4 h4 = *po;
            h4.x = fmaxf(h4.x + a0[r], 0.f);
            h4.y = fmaxf(h4.y + a1[r], 0.f);
            h4.z = fmaxf(h4.z + a2[r], 0.f);
            h4.w = fmaxf(h4.w + a3[r], 0.f);
            *po = h4;
        }
    }
}

extern "C" void kernel_launch(void* const* d_in, const int* in_sizes, int n_in,
                              void* d_out, int out_size, void* d_ws, size_t ws_size,
                              hipStream_t stream)
{
    const float* x      = (const float*)d_in[0];
    const int*   edges  = (const int*)d_in[1];
    const float* Wself  = (const float*)d_in[2];
    const float* bself  = (const float*)d_in[3];
    const float* Wneigh = (const float*)d_in[4];
    const float* bneigh = (const float*)d_in[5];
    float* out = (float*)d_out;

    const int E = in_sizes[1] / 2;
    const int* rows = edges;        // edge_index[0] (sources)
    const int* cols = edges + E;    // edge_index[1] (destinations)

    char* ws_base = (char*)d_ws;
    unsigned int* msgb = (unsigned int*)(ws_base);         // 6.4 MB (bf16x2)
    int*   sorted = (int*)(ws_base + 12800000);            // 3.2 MB block-major
    int*   off    = (int*)(ws_base + 16000000);            // 1.6 MB
    uint4* wfrag  = (uint4*)(ws_base + 17700000);          // 16 KB frag-major W

    k_prep<<<8, 128, 0, stream>>>(Wself, Wneigh, wfrag);

    const int bP = (NN + 31) / 32;   // 1563 proj blocks
    k_main<<<NBLK + bP, 256, 0, stream>>>(rows, cols, sorted, off, E,
                                          x, bself, bneigh,
                                          (const short8*)wfrag, out, msgb);
    k_gfin3<<<NB, 512, 0, stream>>>(msgb, off, sorted, out, E);
}